// Round 4
// baseline (74680.286 us; speedup 1.0000x reference)
//
#include <hip/hip_runtime.h>
#include <hip/hip_cooperative_groups.h>

namespace cg = cooperative_groups;

#define TSTEP 128
#define LATD 256

// ---------------------------------------------------------------------------
// Persistent cooperative kernel, fp32. Grid 256 x 512.
// Activations transposed [feature][batch=64] (lane-coalesced on batch for
// stores, uniform float4 loads in matmuls). Weight reads are lane=column
// coalesced (256B/wave-load, full line utilization) — fixes R3's 4.3x
// over-fetch + latency stalls.
// Folds (validated R3):
//   Wvo = Wv@Wo ; Wvoih = Wvo@Wih0 ; bfold = (bv@Wo+bo)@Wih0 + bih0
//   WhW1 = Wh@w1 ; bhw1 = bh@w1 + b1
// Step = 6 phases: gru0-mm(Ksplit4) / gru0-combine / gru1-mm(Ksplit4) /
//                  gru1-combine / {t1-mm, nz-mm->out} / gin-mm
// ---------------------------------------------------------------------------

struct P {
  const float *z, *w1, *b1, *w2, *b2, *Wv, *bv, *Wo, *bo;
  const float *Wih0, *Whh0, *bih0, *bhh0, *Wih1, *Whh1, *bih1, *bhh1, *Wh, *bh;
  float *out;
  float *Wvoih, *WhW1, *part /*aliases Wvo*/, *bvo, *bfold, *bhw1;
  float *t1, *gin, *h1, *h2;
};

// ---- prologue helpers (validated in R3) -----------------------------------
template <int J, int N, int CPT>
__device__ inline void matmat(const float* __restrict__ A, const float* __restrict__ B,
                              float* __restrict__ C) {
  const int tid = threadIdx.x;
  const int r = blockIdx.x * 4 + (tid >> 7);
  const int c0 = tid & 127;
  float acc[CPT];
#pragma unroll
  for (int i = 0; i < CPT; ++i) acc[i] = 0.f;
  const float* ar = A + r * J;
#pragma unroll 2
  for (int j = 0; j < J; ++j) {
    float av = ar[j];
    const float* br = B + j * N + c0;
#pragma unroll
    for (int i = 0; i < CPT; ++i) acc[i] = fmaf(av, br[i * 128], acc[i]);
  }
  float* cr = C + r * N + c0;
#pragma unroll
  for (int i = 0; i < CPT; ++i) cr[i * 128] = acc[i];
}

__device__ inline void vecmat(const float* __restrict__ v, const float* __restrict__ M,
                              const float* __restrict__ badd, float* __restrict__ outv,
                              int J, int N, int blk0, int nblk) {
  int b = blockIdx.x;
  if (b < blk0 || b >= blk0 + nblk) return;
  int gid = (b - blk0) * 512 + threadIdx.x;
  if (gid >= N) return;
  float acc = 0.f;
#pragma unroll 4
  for (int j = 0; j < J; ++j) acc = fmaf(v[j], M[j * N + gid], acc);
  outv[gid] = acc + badd[gid];
}

__device__ inline void gemv1024(const float* __restrict__ A, const float* __restrict__ W,
                                const float* __restrict__ bias, int K, int relu,
                                float* __restrict__ C, float* __restrict__ C2,
                                float* __restrict__ C3, float* red) {
  const int tid = threadIdx.x;
  const int m = tid & 63, w = tid >> 6;
  const int j = w & 3, hh = w >> 2;
  const int c = blockIdx.x * 4 + j;
  const int kh = K >> 1;
  const float* a = A + m + (hh * kh) * 64;
  const float* wp = W + c + (hh * kh) * 1024;
  float acc = 0.f;
#pragma unroll 8
  for (int k = 0; k < kh; ++k) acc = fmaf(a[k * 64], wp[k * 1024], acc);
  if (hh) red[j * 64 + m] = acc;
  __syncthreads();
  if (!hh) {
    float v = acc + red[j * 64 + m] + bias[c];
    if (relu) v = fmaxf(v, 0.f);
    C[c * 64 + m] = v;
    if (C2) C2[c * 64 + m] = v;
    if (C3) C3[c * 64 + m] = v;
  }
  __syncthreads();
}

// ---- main-loop matmul tile: 64 cols (lane=col, coalesced W) x 64 batches ---
// Each lane: 8 accumulators (8 batch rows), 8 FMA per coalesced weight load.
__device__ __forceinline__ void mm_tile(const float* __restrict__ W, int ldw,
                                        const float* __restrict__ act,
                                        int c0, int k0, int kn, float acc[8]) {
  const int lane = threadIdx.x & 63;
  const int m0 = (threadIdx.x >> 6) * 8;
  const float* wp = W + (size_t)k0 * ldw + c0 + lane;
  const float* ap = act + k0 * 64 + m0;
#pragma unroll 4
  for (int k = 0; k < kn; ++k) {
    float w = wp[(size_t)k * ldw];
    float4 a0 = *(const float4*)(ap + k * 64);
    float4 a1 = *(const float4*)(ap + k * 64 + 4);
    acc[0] = fmaf(w, a0.x, acc[0]); acc[1] = fmaf(w, a0.y, acc[1]);
    acc[2] = fmaf(w, a0.z, acc[2]); acc[3] = fmaf(w, a0.w, acc[3]);
    acc[4] = fmaf(w, a1.x, acc[4]); acc[5] = fmaf(w, a1.y, acc[5]);
    acc[6] = fmaf(w, a1.z, acc[6]); acc[7] = fmaf(w, a1.w, acc[7]);
  }
}

// GRU matmul phase: virtual K = [x:0..1023 | h:1024..2047], Ksplit4.
// Blocks 0..191: g=b>>2 (64-col group of 3072 gate cols), s=b&3 (512-vk slice).
// partial layout: part[(s*3072 + col)*64 + m]
__device__ inline void gru_mm(const float* __restrict__ Wx, const float* __restrict__ actx,
                              const float* __restrict__ Wh, const float* __restrict__ acth,
                              float* __restrict__ part) {
  int b = blockIdx.x;
  if (b >= 192) return;
  int g = b >> 2, s = b & 3;
  int c0 = g * 64;
  float acc[8] = {0.f, 0.f, 0.f, 0.f, 0.f, 0.f, 0.f, 0.f};
  if (s < 2) mm_tile(Wx, 3072, actx, c0, s * 512, 512, acc);
  else       mm_tile(Wh, 3072, acth, c0, (s - 2) * 512, 512, acc);
  const int lane = threadIdx.x & 63;
  const int m0 = (threadIdx.x >> 6) * 8;
  float* pp = part + (size_t)(s * 3072 + c0 + lane) * 64 + m0;
#pragma unroll
  for (int j = 0; j < 8; ++j) pp[j] = acc[j];
}

// GRU combine: gates + in-place h update. 64 blocks x 512 threads x 2 elems.
// ia = x-slices (s=0,1) of n-gate; na = h-slices (s=2,3).
__device__ inline void gru_comb(const float* __restrict__ part,
                                const float* __restrict__ bx, const float* __restrict__ bm,
                                float* __restrict__ h) {
  if (blockIdx.x >= 64) return;
  int base = blockIdx.x * 1024 + threadIdx.x;
#pragma unroll
  for (int half = 0; half < 2; ++half) {
    int idx = base + half * 512;
    int c = idx >> 6, m = idx & 63;
    float ra = 0.f, za = 0.f;
#pragma unroll
    for (int s = 0; s < 4; ++s) {
      ra += part[(size_t)(s * 3072 + c) * 64 + m];
      za += part[(size_t)(s * 3072 + 1024 + c) * 64 + m];
    }
    float ia = part[(size_t)(2048 + c) * 64 + m] +
               part[(size_t)(3072 + 2048 + c) * 64 + m];
    float na = part[(size_t)(2 * 3072 + 2048 + c) * 64 + m] +
               part[(size_t)(3 * 3072 + 2048 + c) * 64 + m];
    float r  = 1.f / (1.f + expf(-(ra + bx[c] + bm[c])));
    float zg = 1.f / (1.f + expf(-(za + bx[1024 + c] + bm[1024 + c])));
    float nn = tanhf(ia + bx[2048 + c] + r * (na + bm[2048 + c]));
    float hp = h[c * 64 + m];
    h[c * 64 + m] = (1.f - zg) * nn + zg * hp;
  }
}

__global__ __launch_bounds__(512) void persist(P p) {
  cg::grid_group grid = cg::this_grid();
  __shared__ float red[256];
  const int lane = threadIdx.x & 63;
  const int m0 = (threadIdx.x >> 6) * 8;

  // ---- prologue (5 syncs) ----
  if (threadIdx.x < 64) {  // zT -> h1 region (dead until phase 3 read)
    int i = blockIdx.x * 64 + threadIdx.x;
    int m = i >> 8, l = i & 255;
    p.h1[l * 64 + m] = p.z[i];
  }
  matmat<1024, 1024, 8>(p.Wv, p.Wo, p.part);          // Wvo (aliased in part)
  vecmat(p.bh, p.w1, p.b1, p.bhw1, 256, 1024, 0, 2);
  vecmat(p.bv, p.Wo, p.bo, p.bvo, 1024, 1024, 2, 2);
  grid.sync();
  matmat<1024, 3072, 24>(p.part, p.Wih0, p.Wvoih);    // Wvoih = Wvo@Wih0
  vecmat(p.bvo, p.Wih0, p.bih0, p.bfold, 1024, 3072, 0, 6);
  grid.sync();
  matmat<256, 1024, 8>(p.Wh, p.w1, p.WhW1);           // WhW1 = Wh@w1 (Wvo dead)
  grid.sync();
  gemv1024(p.h1, p.w1, p.b1, 256, 1, p.t1, nullptr, nullptr, red);   // relu(z@w1+b1)
  grid.sync();
  gemv1024(p.t1, p.w2, p.b2, 1024, 0, p.h1, p.h2, p.gin, red);       // h0p -> h1,h2,gin
  grid.sync();

  // ---- time loop: 6 phases/step ----
  for (int t = 0; t < TSTEP; ++t) {
    gru_mm(p.Wvoih, p.gin, p.Whh0, p.h1, p.part);          // P1
    grid.sync();
    gru_comb(p.part, p.bfold, p.bhh0, p.h1);               // P2: h1 updated
    grid.sync();
    gru_mm(p.Wih1, p.h1, p.Whh1, p.h2, p.part);            // P3
    grid.sync();
    gru_comb(p.part, p.bih1, p.bhh1, p.h2);                // P4: h2 updated
    grid.sync();
    {                                                      // P5: t1 + nz->out
      int b = blockIdx.x;
      if (b < 16) {
        float acc[8] = {0.f, 0.f, 0.f, 0.f, 0.f, 0.f, 0.f, 0.f};
        mm_tile(p.WhW1, 1024, p.h2, b * 64, 0, 1024, acc);
        int c = b * 64 + lane;
        float bb = p.bhw1[c];
#pragma unroll
        for (int j = 0; j < 8; ++j)
          p.t1[c * 64 + m0 + j] = fmaxf(acc[j] + bb, 0.f);
      } else if (b < 20) {
        float acc[8] = {0.f, 0.f, 0.f, 0.f, 0.f, 0.f, 0.f, 0.f};
        int c0 = (b - 16) * 64;
        mm_tile(p.Wh, 256, p.h2, c0, 0, 1024, acc);
        int c = c0 + lane;
        float bb = p.bh[c];
#pragma unroll
        for (int j = 0; j < 8; ++j)
          p.out[(size_t)((m0 + j) * TSTEP + t) * LATD + c] = acc[j] + bb;
      }
    }
    grid.sync();
    {                                                      // P6: gin = relu(t1@w2+b2)
      int b = blockIdx.x;
      if (b < 16) {
        float acc[8] = {0.f, 0.f, 0.f, 0.f, 0.f, 0.f, 0.f, 0.f};
        mm_tile(p.w2, 1024, p.t1, b * 64, 0, 1024, acc);
        int c = b * 64 + lane;
        float bb = p.b2[c];
#pragma unroll
        for (int j = 0; j < 8; ++j)
          p.gin[c * 64 + m0 + j] = fmaxf(acc[j] + bb, 0.f);
      }
    }
    grid.sync();
  }
}

// ---------------------------------------------------------------------------
// Fallback path (round-2 verified multi-kernel).
// ---------------------------------------------------------------------------
__global__ void fb_transpose(const float* __restrict__ z, float* __restrict__ zT) {
  int i = blockIdx.x * 256 + threadIdx.x;
  int m = i >> 8, l = i & 255;
  zT[l * 64 + m] = z[i];
}
__global__ void fb_copy2(const float* __restrict__ s, float* __restrict__ d1,
                         float* __restrict__ d2) {
  int i = blockIdx.x * 256 + threadIdx.x;
  float v = s[i]; d1[i] = v; d2[i] = v;
}
template <int ACT>
__global__ void fb_gemm(const float* __restrict__ A_T, const float* __restrict__ W,
                        const float* __restrict__ bias, float* __restrict__ C_T,
                        int K, int N, float* __restrict__ outp, int tstep) {
  const int m = threadIdx.x & 63;
  const int wv = threadIdx.x >> 6;
  const int c = blockIdx.x * 4 + wv;
  float acc0 = 0.f, acc1 = 0.f;
  const float* ap = A_T + m;
  const float* wp = W + c;
#pragma unroll 4
  for (int k = 0; k + 1 < K; k += 2) {
    acc0 = fmaf(ap[k * 64], wp[k * N], acc0);
    acc1 = fmaf(ap[(k + 1) * 64], wp[(k + 1) * N], acc1);
  }
  float v0 = acc0 + acc1 + bias[c];
  if (ACT) v0 = fmaxf(v0, 0.f);
  C_T[c * 64 + m] = v0;
  if (outp != nullptr) outp[(m * TSTEP + tstep) * LATD + c] = v0;
}
__global__ void fb_gru(const float* __restrict__ xT, const float* __restrict__ hT,
                       const float* __restrict__ Wih, const float* __restrict__ Whh,
                       const float* __restrict__ bih, const float* __restrict__ bhh,
                       float* __restrict__ hnT) {
  const int m = threadIdx.x & 63;
  const int wv = threadIdx.x >> 6;
  const int c = blockIdx.x * 4 + wv;
  float racc = 0, zacc = 0, iacc = 0, nacc = 0;
  const float* xp = xT + m;
  const float* hp = hT + m;
  const float* wi = Wih + c;
  const float* wh = Whh + c;
#pragma unroll 2
  for (int k = 0; k < 1024; ++k) {
    float a = xp[k * 64];
    float h = hp[k * 64];
    const float* wik = wi + k * 3072;
    const float* whk = wh + k * 3072;
    racc = fmaf(a, wik[0], racc); racc = fmaf(h, whk[0], racc);
    zacc = fmaf(a, wik[1024], zacc); zacc = fmaf(h, whk[1024], zacc);
    iacc = fmaf(a, wik[2048], iacc);
    nacc = fmaf(h, whk[2048], nacc);
  }
  float r = 1.f / (1.f + expf(-(racc + bih[c] + bhh[c])));
  float zg = 1.f / (1.f + expf(-(zacc + bih[1024 + c] + bhh[1024 + c])));
  float nn = tanhf(iacc + bih[2048 + c] + r * (nacc + bhh[2048 + c]));
  hnT[c * 64 + m] = (1.f - zg) * nn + zg * hT[c * 64 + m];
}

extern "C" void kernel_launch(void* const* d_in, const int* in_sizes, int n_in,
                              void* d_out, int out_size, void* d_ws, size_t ws_size,
                              hipStream_t stream) {
  const float* z_start = (const float*)d_in[0];
  const float* w1 = (const float*)d_in[2];
  const float* b1 = (const float*)d_in[3];
  const float* w2 = (const float*)d_in[4];
  const float* b2 = (const float*)d_in[5];
  const float* Wv = (const float*)d_in[10];
  const float* bv = (const float*)d_in[11];
  const float* Wo = (const float*)d_in[12];
  const float* bo = (const float*)d_in[13];
  const float* Wih0 = (const float*)d_in[14];
  const float* Whh0 = (const float*)d_in[15];
  const float* bih0 = (const float*)d_in[16];
  const float* bhh0 = (const float*)d_in[17];
  const float* Wih1 = (const float*)d_in[18];
  const float* Whh1 = (const float*)d_in[19];
  const float* bih1 = (const float*)d_in[20];
  const float* bhh1 = (const float*)d_in[21];
  const float* Wh = (const float*)d_in[22];
  const float* bh = (const float*)d_in[23];
  float* out = (float*)d_out;
  float* ws = (float*)d_ws;

  // floats: Wvoih 3145728 + WhW1 1048576 + part/Wvo 1048576 + t1/gin/h1/h2
  //         4*65536 + bvo 1024 + bfold 3072 + bhw1 1024 = 5510144 (~22.0 MB)
  const size_t need = (size_t)5510144 * 4;
  if (ws_size >= need) {
    P p;
    p.z = z_start; p.w1 = w1; p.b1 = b1; p.w2 = w2; p.b2 = b2;
    p.Wv = Wv; p.bv = bv; p.Wo = Wo; p.bo = bo;
    p.Wih0 = Wih0; p.Whh0 = Whh0; p.bih0 = bih0; p.bhh0 = bhh0;
    p.Wih1 = Wih1; p.Whh1 = Whh1; p.bih1 = bih1; p.bhh1 = bhh1;
    p.Wh = Wh; p.bh = bh; p.out = out;
    float* q = ws;
    p.Wvoih = q; q += 3145728;
    p.WhW1 = q; q += 1048576;
    p.part = q; q += 1048576;   // also Wvo during prologue
    p.t1 = q; q += 65536;
    p.gin = q; q += 65536;
    p.h1 = q; q += 65536;
    p.h2 = q; q += 65536;
    p.bvo = q; q += 1024;
    p.bfold = q; q += 3072;
    p.bhw1 = q; q += 1024;
    void* args[] = { &p };
    hipError_t e = hipLaunchCooperativeKernel((const void*)persist, dim3(256),
                                              dim3(512), args, 0, stream);
    if (e == hipSuccess) return;
  }

  // -------- fallback: verified round-2 path --------
  float* zsT = ws;
  float* vT = zsT + 16384;
  float* xaT = vT + 65536;
  float* t1T = xaT + 65536;
  float* ginT = t1T + 65536;
  float* nzT = ginT + 65536;
  float* h1T = nzT + 16384;
  float* h2T = h1T + 2 * 65536;

  fb_transpose<<<64, 256, 0, stream>>>(z_start, zsT);
  fb_gemm<1><<<256, 256, 0, stream>>>(zsT, w1, b1, t1T, 256, 1024, nullptr, 0);
  fb_gemm<0><<<256, 256, 0, stream>>>(t1T, w2, b2, h1T, 1024, 1024, nullptr, 0);
  fb_copy2<<<256, 256, 0, stream>>>(h1T, h2T, ginT);
  for (int t = 0; t < TSTEP; ++t) {
    float* h1p = h1T + (t & 1) * 65536;
    float* h1n = h1T + ((t + 1) & 1) * 65536;
    float* h2p = h2T + (t & 1) * 65536;
    float* h2n = h2T + ((t + 1) & 1) * 65536;
    fb_gemm<0><<<256, 256, 0, stream>>>(ginT, Wv, bv, vT, 1024, 1024, nullptr, 0);
    fb_gemm<0><<<256, 256, 0, stream>>>(vT, Wo, bo, xaT, 1024, 1024, nullptr, 0);
    fb_gru<<<256, 256, 0, stream>>>(xaT, h1p, Wih0, Whh0, bih0, bhh0, h1n);
    fb_gru<<<256, 256, 0, stream>>>(h1n, h2p, Wih1, Whh1, bih1, bhh1, h2n);
    fb_gemm<0><<<64, 256, 0, stream>>>(h2n, Wh, bh, nzT, 1024, 256, out, t);
    fb_gemm<1><<<256, 256, 0, stream>>>(nzT, w1, b1, t1T, 256, 1024, nullptr, 0);
    fb_gemm<1><<<256, 256, 0, stream>>>(t1T, w2, b2, ginT, 1024, 1024, nullptr, 0);
  }
}

// Round 5
// 71291.595 us; speedup vs baseline: 1.0475x; 1.0475x over previous
//
#include <hip/hip_runtime.h>
#include <hip/hip_cooperative_groups.h>

namespace cg = cooperative_groups;

#define TSTEP 128
#define LATD 256

// ---------------------------------------------------------------------------
// Persistent cooperative kernel, fp32. Grid 256 x 512.
// R4 post-mortem: cg::grid.sync() costs ~90us each (773 syncs = ~70ms idle,
// VALUBusy 3.6%). This round: custom monotonic barrier (atomicAdd + relaxed
// agent-scope spin + __threadfence release/acquire) — everything else held
// fixed from R4 (coalesced weights, 8-acc ILP: FETCH_SIZE 31.9GB -> 4.7GB,
// VALU work ~2.7ms, both verified good).
// Folds (validated R3/R4):
//   Wvo = Wv@Wo ; Wvoih = Wvo@Wih0 ; bfold = (bv@Wo+bo)@Wih0 + bih0
//   WhW1 = Wh@w1 ; bhw1 = bh@w1 + b1
// Step = 6 phases: gru0-mm(Ksplit4) / gru0-comb / gru1-mm(Ksplit4) /
//                  gru1-comb / {t1-mm, nz-mm->out} / gin-mm
// ---------------------------------------------------------------------------

struct P {
  const float *z, *w1, *b1, *w2, *b2, *Wv, *bv, *Wo, *bo;
  const float *Wih0, *Whh0, *bih0, *bhh0, *Wih1, *Whh1, *bih1, *bhh1, *Wh, *bh;
  float *out;
  float *Wvoih, *WhW1, *part /*aliases Wvo*/, *bvo, *bfold, *bhw1;
  float *t1, *gin, *h1, *h2;
  unsigned *bar;
};

// Fast grid barrier: monotonic count, one atomic per block, agent-scope spin.
// __threadfence() provides release (wbl2) before arrival and acquire (inv)
// after detection — required for cross-XCD visibility (G16).
__device__ __forceinline__ void gbar(unsigned* __restrict__ cnt, unsigned& tgt) {
  __syncthreads();
  tgt += 256u;
  if (threadIdx.x == 0) {
    __threadfence();
    atomicAdd(cnt, 1u);
    while (__hip_atomic_load(cnt, __ATOMIC_RELAXED, __HIP_MEMORY_SCOPE_AGENT) < tgt) {
      __builtin_amdgcn_s_sleep(1);
    }
    __threadfence();
  }
  __syncthreads();
}

// ---- prologue helpers (validated R3/R4) -----------------------------------
template <int J, int N, int CPT>
__device__ inline void matmat(const float* __restrict__ A, const float* __restrict__ B,
                              float* __restrict__ C) {
  const int tid = threadIdx.x;
  const int r = blockIdx.x * 4 + (tid >> 7);
  const int c0 = tid & 127;
  float acc[CPT];
#pragma unroll
  for (int i = 0; i < CPT; ++i) acc[i] = 0.f;
  const float* ar = A + r * J;
#pragma unroll 2
  for (int j = 0; j < J; ++j) {
    float av = ar[j];
    const float* br = B + j * N + c0;
#pragma unroll
    for (int i = 0; i < CPT; ++i) acc[i] = fmaf(av, br[i * 128], acc[i]);
  }
  float* cr = C + r * N + c0;
#pragma unroll
  for (int i = 0; i < CPT; ++i) cr[i * 128] = acc[i];
}

__device__ inline void vecmat(const float* __restrict__ v, const float* __restrict__ M,
                              const float* __restrict__ badd, float* __restrict__ outv,
                              int J, int N, int blk0, int nblk) {
  int b = blockIdx.x;
  if (b < blk0 || b >= blk0 + nblk) return;
  int gid = (b - blk0) * 512 + threadIdx.x;
  if (gid >= N) return;
  float acc = 0.f;
#pragma unroll 4
  for (int j = 0; j < J; ++j) acc = fmaf(v[j], M[j * N + gid], acc);
  outv[gid] = acc + badd[gid];
}

__device__ inline void gemv1024(const float* __restrict__ A, const float* __restrict__ W,
                                const float* __restrict__ bias, int K, int relu,
                                float* __restrict__ C, float* __restrict__ C2,
                                float* __restrict__ C3, float* red) {
  const int tid = threadIdx.x;
  const int m = tid & 63, w = tid >> 6;
  const int j = w & 3, hh = w >> 2;
  const int c = blockIdx.x * 4 + j;
  const int kh = K >> 1;
  const float* a = A + m + (hh * kh) * 64;
  const float* wp = W + c + (hh * kh) * 1024;
  float acc = 0.f;
#pragma unroll 8
  for (int k = 0; k < kh; ++k) acc = fmaf(a[k * 64], wp[k * 1024], acc);
  if (hh) red[j * 64 + m] = acc;
  __syncthreads();
  if (!hh) {
    float v = acc + red[j * 64 + m] + bias[c];
    if (relu) v = fmaxf(v, 0.f);
    C[c * 64 + m] = v;
    if (C2) C2[c * 64 + m] = v;
    if (C3) C3[c * 64 + m] = v;
  }
  __syncthreads();
}

// ---- main-loop matmul tile: 64 cols (lane=col, coalesced W) x 64 batches ---
__device__ __forceinline__ void mm_tile(const float* __restrict__ W, int ldw,
                                        const float* __restrict__ act,
                                        int c0, int k0, int kn, float acc[8]) {
  const int lane = threadIdx.x & 63;
  const int m0 = (threadIdx.x >> 6) * 8;
  const float* wp = W + (size_t)k0 * ldw + c0 + lane;
  const float* ap = act + k0 * 64 + m0;
#pragma unroll 4
  for (int k = 0; k < kn; ++k) {
    float w = wp[(size_t)k * ldw];
    float4 a0 = *(const float4*)(ap + k * 64);
    float4 a1 = *(const float4*)(ap + k * 64 + 4);
    acc[0] = fmaf(w, a0.x, acc[0]); acc[1] = fmaf(w, a0.y, acc[1]);
    acc[2] = fmaf(w, a0.z, acc[2]); acc[3] = fmaf(w, a0.w, acc[3]);
    acc[4] = fmaf(w, a1.x, acc[4]); acc[5] = fmaf(w, a1.y, acc[5]);
    acc[6] = fmaf(w, a1.z, acc[6]); acc[7] = fmaf(w, a1.w, acc[7]);
  }
}

// GRU matmul phase: virtual K = [x:0..1023 | h:1024..2047], Ksplit4.
__device__ inline void gru_mm(const float* __restrict__ Wx, const float* __restrict__ actx,
                              const float* __restrict__ Wh, const float* __restrict__ acth,
                              float* __restrict__ part) {
  int b = blockIdx.x;
  if (b >= 192) return;
  int g = b >> 2, s = b & 3;
  int c0 = g * 64;
  float acc[8] = {0.f, 0.f, 0.f, 0.f, 0.f, 0.f, 0.f, 0.f};
  if (s < 2) mm_tile(Wx, 3072, actx, c0, s * 512, 512, acc);
  else       mm_tile(Wh, 3072, acth, c0, (s - 2) * 512, 512, acc);
  const int lane = threadIdx.x & 63;
  const int m0 = (threadIdx.x >> 6) * 8;
  float* pp = part + (size_t)(s * 3072 + c0 + lane) * 64 + m0;
#pragma unroll
  for (int j = 0; j < 8; ++j) pp[j] = acc[j];
}

// GRU combine: gates + in-place h update. 64 blocks x 512 threads x 2 elems.
__device__ inline void gru_comb(const float* __restrict__ part,
                                const float* __restrict__ bx, const float* __restrict__ bm,
                                float* __restrict__ h) {
  if (blockIdx.x >= 64) return;
  int base = blockIdx.x * 1024 + threadIdx.x;
#pragma unroll
  for (int half = 0; half < 2; ++half) {
    int idx = base + half * 512;
    int c = idx >> 6, m = idx & 63;
    float ra = 0.f, za = 0.f;
#pragma unroll
    for (int s = 0; s < 4; ++s) {
      ra += part[(size_t)(s * 3072 + c) * 64 + m];
      za += part[(size_t)(s * 3072 + 1024 + c) * 64 + m];
    }
    float ia = part[(size_t)(2048 + c) * 64 + m] +
               part[(size_t)(3072 + 2048 + c) * 64 + m];
    float na = part[(size_t)(2 * 3072 + 2048 + c) * 64 + m] +
               part[(size_t)(3 * 3072 + 2048 + c) * 64 + m];
    float r  = 1.f / (1.f + expf(-(ra + bx[c] + bm[c])));
    float zg = 1.f / (1.f + expf(-(za + bx[1024 + c] + bm[1024 + c])));
    float nn = tanhf(ia + bx[2048 + c] + r * (na + bm[2048 + c]));
    float hp = h[c * 64 + m];
    h[c * 64 + m] = (1.f - zg) * nn + zg * hp;
  }
}

__global__ __launch_bounds__(512) void persist(P p) {
  cg::grid_group grid = cg::this_grid();
  __shared__ float red[256];
  const int lane = threadIdx.x & 63;
  const int m0 = (threadIdx.x >> 6) * 8;
  unsigned tgt = 0;

  // ---- barrier init: one slow cg sync publishes *bar = 0 ----
  if (blockIdx.x == 0 && threadIdx.x == 0) atomicExch(p.bar, 0u);
  grid.sync();

  // ---- prologue (5 fast barriers) ----
  if (threadIdx.x < 64) {  // zT -> h1 region (dead until phase 4 read)
    int i = blockIdx.x * 64 + threadIdx.x;
    int m = i >> 8, l = i & 255;
    p.h1[l * 64 + m] = p.z[i];
  }
  matmat<1024, 1024, 8>(p.Wv, p.Wo, p.part);          // Wvo (aliased in part)
  vecmat(p.bh, p.w1, p.b1, p.bhw1, 256, 1024, 0, 2);
  vecmat(p.bv, p.Wo, p.bo, p.bvo, 1024, 1024, 2, 2);
  gbar(p.bar, tgt);
  matmat<1024, 3072, 24>(p.part, p.Wih0, p.Wvoih);    // Wvoih = Wvo@Wih0
  vecmat(p.bvo, p.Wih0, p.bih0, p.bfold, 1024, 3072, 0, 6);
  gbar(p.bar, tgt);
  matmat<256, 1024, 8>(p.Wh, p.w1, p.WhW1);           // WhW1 = Wh@w1 (Wvo dead)
  gbar(p.bar, tgt);
  gemv1024(p.h1, p.w1, p.b1, 256, 1, p.t1, nullptr, nullptr, red);   // relu(z@w1+b1)
  gbar(p.bar, tgt);
  gemv1024(p.t1, p.w2, p.b2, 1024, 0, p.h1, p.h2, p.gin, red);       // h0p -> h1,h2,gin
  gbar(p.bar, tgt);

  // ---- time loop: 6 phases/step ----
  for (int t = 0; t < TSTEP; ++t) {
    gru_mm(p.Wvoih, p.gin, p.Whh0, p.h1, p.part);          // P1
    gbar(p.bar, tgt);
    gru_comb(p.part, p.bfold, p.bhh0, p.h1);               // P2: h1 updated
    gbar(p.bar, tgt);
    gru_mm(p.Wih1, p.h1, p.Whh1, p.h2, p.part);            // P3
    gbar(p.bar, tgt);
    gru_comb(p.part, p.bih1, p.bhh1, p.h2);                // P4: h2 updated
    gbar(p.bar, tgt);
    {                                                      // P5: t1 + nz->out
      int b = blockIdx.x;
      if (b < 16) {
        float acc[8] = {0.f, 0.f, 0.f, 0.f, 0.f, 0.f, 0.f, 0.f};
        mm_tile(p.WhW1, 1024, p.h2, b * 64, 0, 1024, acc);
        int c = b * 64 + lane;
        float bb = p.bhw1[c];
#pragma unroll
        for (int j = 0; j < 8; ++j)
          p.t1[c * 64 + m0 + j] = fmaxf(acc[j] + bb, 0.f);
      } else if (b < 20) {
        float acc[8] = {0.f, 0.f, 0.f, 0.f, 0.f, 0.f, 0.f, 0.f};
        int c0 = (b - 16) * 64;
        mm_tile(p.Wh, 256, p.h2, c0, 0, 1024, acc);
        int c = c0 + lane;
        float bb = p.bh[c];
#pragma unroll
        for (int j = 0; j < 8; ++j)
          p.out[(size_t)((m0 + j) * TSTEP + t) * LATD + c] = acc[j] + bb;
      }
    }
    gbar(p.bar, tgt);
    {                                                      // P6: gin = relu(t1@w2+b2)
      int b = blockIdx.x;
      if (b < 16) {
        float acc[8] = {0.f, 0.f, 0.f, 0.f, 0.f, 0.f, 0.f, 0.f};
        mm_tile(p.w2, 1024, p.t1, b * 64, 0, 1024, acc);
        int c = b * 64 + lane;
        float bb = p.b2[c];
#pragma unroll
        for (int j = 0; j < 8; ++j)
          p.gin[c * 64 + m0 + j] = fmaxf(acc[j] + bb, 0.f);
      }
    }
    gbar(p.bar, tgt);
  }
}

// ---------------------------------------------------------------------------
// Fallback path (round-2 verified multi-kernel).
// ---------------------------------------------------------------------------
__global__ void fb_transpose(const float* __restrict__ z, float* __restrict__ zT) {
  int i = blockIdx.x * 256 + threadIdx.x;
  int m = i >> 8, l = i & 255;
  zT[l * 64 + m] = z[i];
}
__global__ void fb_copy2(const float* __restrict__ s, float* __restrict__ d1,
                         float* __restrict__ d2) {
  int i = blockIdx.x * 256 + threadIdx.x;
  float v = s[i]; d1[i] = v; d2[i] = v;
}
template <int ACT>
__global__ void fb_gemm(const float* __restrict__ A_T, const float* __restrict__ W,
                        const float* __restrict__ bias, float* __restrict__ C_T,
                        int K, int N, float* __restrict__ outp, int tstep) {
  const int m = threadIdx.x & 63;
  const int wv = threadIdx.x >> 6;
  const int c = blockIdx.x * 4 + wv;
  float acc0 = 0.f, acc1 = 0.f;
  const float* ap = A_T + m;
  const float* wp = W + c;
#pragma unroll 4
  for (int k = 0; k + 1 < K; k += 2) {
    acc0 = fmaf(ap[k * 64], wp[k * N], acc0);
    acc1 = fmaf(ap[(k + 1) * 64], wp[(k + 1) * N], acc1);
  }
  float v0 = acc0 + acc1 + bias[c];
  if (ACT) v0 = fmaxf(v0, 0.f);
  C_T[c * 64 + m] = v0;
  if (outp != nullptr) outp[(m * TSTEP + tstep) * LATD + c] = v0;
}
__global__ void fb_gru(const float* __restrict__ xT, const float* __restrict__ hT,
                       const float* __restrict__ Wih, const float* __restrict__ Whh,
                       const float* __restrict__ bih, const float* __restrict__ bhh,
                       float* __restrict__ hnT) {
  const int m = threadIdx.x & 63;
  const int wv = threadIdx.x >> 6;
  const int c = blockIdx.x * 4 + wv;
  float racc = 0, zacc = 0, iacc = 0, nacc = 0;
  const float* xp = xT + m;
  const float* hp = hT + m;
  const float* wi = Wih + c;
  const float* wh = Whh + c;
#pragma unroll 2
  for (int k = 0; k < 1024; ++k) {
    float a = xp[k * 64];
    float h = hp[k * 64];
    const float* wik = wi + k * 3072;
    const float* whk = wh + k * 3072;
    racc = fmaf(a, wik[0], racc); racc = fmaf(h, whk[0], racc);
    zacc = fmaf(a, wik[1024], zacc); zacc = fmaf(h, whk[1024], zacc);
    iacc = fmaf(a, wik[2048], iacc);
    nacc = fmaf(h, whk[2048], nacc);
  }
  float r = 1.f / (1.f + expf(-(racc + bih[c] + bhh[c])));
  float zg = 1.f / (1.f + expf(-(zacc + bih[1024 + c] + bhh[1024 + c])));
  float nn = tanhf(iacc + bih[2048 + c] + r * (nacc + bhh[2048 + c]));
  hnT[c * 64 + m] = (1.f - zg) * nn + zg * hT[c * 64 + m];
}

extern "C" void kernel_launch(void* const* d_in, const int* in_sizes, int n_in,
                              void* d_out, int out_size, void* d_ws, size_t ws_size,
                              hipStream_t stream) {
  const float* z_start = (const float*)d_in[0];
  const float* w1 = (const float*)d_in[2];
  const float* b1 = (const float*)d_in[3];
  const float* w2 = (const float*)d_in[4];
  const float* b2 = (const float*)d_in[5];
  const float* Wv = (const float*)d_in[10];
  const float* bv = (const float*)d_in[11];
  const float* Wo = (const float*)d_in[12];
  const float* bo = (const float*)d_in[13];
  const float* Wih0 = (const float*)d_in[14];
  const float* Whh0 = (const float*)d_in[15];
  const float* bih0 = (const float*)d_in[16];
  const float* bhh0 = (const float*)d_in[17];
  const float* Wih1 = (const float*)d_in[18];
  const float* Whh1 = (const float*)d_in[19];
  const float* bih1 = (const float*)d_in[20];
  const float* bhh1 = (const float*)d_in[21];
  const float* Wh = (const float*)d_in[22];
  const float* bh = (const float*)d_in[23];
  float* out = (float*)d_out;
  float* ws = (float*)d_ws;

  // floats: Wvoih 3145728 + WhW1 1048576 + part 1048576 + t1/gin/h1/h2
  //         4*65536 + bvo 1024 + bfold 3072 + bhw1 1024 + bar pad 64
  const size_t need = (size_t)(5510144 + 64) * 4;
  if (ws_size >= need) {
    P p;
    p.z = z_start; p.w1 = w1; p.b1 = b1; p.w2 = w2; p.b2 = b2;
    p.Wv = Wv; p.bv = bv; p.Wo = Wo; p.bo = bo;
    p.Wih0 = Wih0; p.Whh0 = Whh0; p.bih0 = bih0; p.bhh0 = bhh0;
    p.Wih1 = Wih1; p.Whh1 = Whh1; p.bih1 = bih1; p.bhh1 = bhh1;
    p.Wh = Wh; p.bh = bh; p.out = out;
    float* q = ws;
    p.Wvoih = q; q += 3145728;
    p.WhW1 = q; q += 1048576;
    p.part = q; q += 1048576;   // also Wvo during prologue
    p.t1 = q; q += 65536;
    p.gin = q; q += 65536;
    p.h1 = q; q += 65536;
    p.h2 = q; q += 65536;
    p.bvo = q; q += 1024;
    p.bfold = q; q += 3072;
    p.bhw1 = q; q += 1024;
    p.bar = (unsigned*)q; q += 64;
    void* args[] = { &p };
    hipError_t e = hipLaunchCooperativeKernel((const void*)persist, dim3(256),
                                              dim3(512), args, 0, stream);
    if (e == hipSuccess) return;
  }

  // -------- fallback: verified round-2 path --------
  float* zsT = ws;
  float* vT = zsT + 16384;
  float* xaT = vT + 65536;
  float* t1T = xaT + 65536;
  float* ginT = t1T + 65536;
  float* nzT = ginT + 65536;
  float* h1T = nzT + 16384;
  float* h2T = h1T + 2 * 65536;

  fb_transpose<<<64, 256, 0, stream>>>(z_start, zsT);
  fb_gemm<1><<<256, 256, 0, stream>>>(zsT, w1, b1, t1T, 256, 1024, nullptr, 0);
  fb_gemm<0><<<256, 256, 0, stream>>>(t1T, w2, b2, h1T, 1024, 1024, nullptr, 0);
  fb_copy2<<<256, 256, 0, stream>>>(h1T, h2T, ginT);
  for (int t = 0; t < TSTEP; ++t) {
    float* h1p = h1T + (t & 1) * 65536;
    float* h1n = h1T + ((t + 1) & 1) * 65536;
    float* h2p = h2T + (t & 1) * 65536;
    float* h2n = h2T + ((t + 1) & 1) * 65536;
    fb_gemm<0><<<256, 256, 0, stream>>>(ginT, Wv, bv, vT, 1024, 1024, nullptr, 0);
    fb_gemm<0><<<256, 256, 0, stream>>>(vT, Wo, bo, xaT, 1024, 1024, nullptr, 0);
    fb_gru<<<256, 256, 0, stream>>>(xaT, h1p, Wih0, Whh0, bih0, bhh0, h1n);
    fb_gru<<<256, 256, 0, stream>>>(h1n, h2p, Wih1, Whh1, bih1, bhh1, h2n);
    fb_gemm<0><<<64, 256, 0, stream>>>(h2n, Wh, bh, nzT, 1024, 256, out, t);
    fb_gemm<1><<<256, 256, 0, stream>>>(nzT, w1, b1, t1T, 256, 1024, nullptr, 0);
    fb_gemm<1><<<256, 256, 0, stream>>>(t1T, w2, b2, ginT, 1024, 1024, nullptr, 0);
  }
}